// Round 1
// 537.722 us; speedup vs baseline: 1.0968x; 1.0968x over previous
//
#include <hip/hip_runtime.h>
#include <hip/hip_fp16.h>

#define N_NODES 50000
#define BSH 7                 // bucket = dst >> 7
#define BMASK 127
#define NBUCK 391             // ceil(50000/128)
#define EPB 4096              // edges per block in bucket hist/fill
#define CAPB 5120             // max edges per bucket (mean 4096, sigma ~64)

// ---------------------------------------------------------------------------
// A1: bucket histogram. LDS hist per block, one global atomic per (blk,bucket).
// ---------------------------------------------------------------------------
__global__ __launch_bounds__(256) void k_bhist(
    const int* __restrict__ dst, int* __restrict__ bcnt, int E)
{
    __shared__ int hist[NBUCK];
    for (int i = threadIdx.x; i < NBUCK; i += 256) hist[i] = 0;
    __syncthreads();
    int base = blockIdx.x * EPB;
    int lim  = min(base + EPB, E);
    for (int e = base + threadIdx.x; e < lim; e += 256)
        atomicAdd(&hist[dst[e] >> BSH], 1);
    __syncthreads();
    for (int i = threadIdx.x; i < NBUCK; i += 256)
        if (hist[i]) atomicAdd(&bcnt[i], hist[i]);
}

// ---------------------------------------------------------------------------
// A2: exclusive scan of 391 bucket counts.
// ---------------------------------------------------------------------------
__global__ __launch_bounds__(512) void k_bscan(
    const int* __restrict__ bcnt, int* __restrict__ boff,
    int* __restrict__ bcur, int E)
{
    __shared__ int tmp[NBUCK];
    for (int i = threadIdx.x; i < NBUCK; i += 512) tmp[i] = bcnt[i];
    __syncthreads();
    if (threadIdx.x == 0) {
        int run = 0;
        for (int i = 0; i < NBUCK; ++i) { int c = tmp[i]; tmp[i] = run; run += c; }
    }
    __syncthreads();
    for (int i = threadIdx.x; i < NBUCK; i += 512) {
        boff[i] = tmp[i];
        bcur[i] = tmp[i];
    }
    if (threadIdx.x == 0) boff[NBUCK] = E;
}

// ---------------------------------------------------------------------------
// A3: bucketed fill. Payload is now int2 {(e<<7)|(dst&127), src[e]} so the
// sort can emit src-sorted-by-dst (kills the src[csr[i]] indirection later).
// src[base+idx] is a coalesced re-read (L2-hot from this block's own pass).
// ---------------------------------------------------------------------------
__global__ __launch_bounds__(256) void k_bfill(
    const int* __restrict__ dst, const int* __restrict__ src,
    int* __restrict__ bcur, int2* __restrict__ ebuf, int E)
{
    __shared__ unsigned short dstv[EPB];
    __shared__ int hist[NBUCK];
    __shared__ int basev[NBUCK];
    __shared__ int cur[NBUCK];
    for (int i = threadIdx.x; i < NBUCK; i += 256) hist[i] = 0;
    __syncthreads();
    int base = blockIdx.x * EPB;
    int lim  = min(base + EPB, E);
    for (int e = base + threadIdx.x; e < lim; e += 256) {
        int d = dst[e];
        dstv[e - base] = (unsigned short)d;
        atomicAdd(&hist[d >> BSH], 1);
    }
    __syncthreads();
    for (int i = threadIdx.x; i < NBUCK; i += 256) {
        int c = hist[i];
        cur[i] = 0;
        if (c) basev[i] = atomicAdd(&bcur[i], c);
    }
    __syncthreads();
    int n = lim - base;
    for (int idx = threadIdx.x; idx < n; idx += 256) {
        int d = (int)dstv[idx];
        int b = d >> BSH;
        int p = basev[b] + atomicAdd(&cur[b], 1);
        ebuf[p] = make_int2(((base + idx) << BSH) | (d & BMASK), src[base + idx]);
    }
}

// ---------------------------------------------------------------------------
// B: per-bucket LDS sort of int2 payload. Emits csr (sorted edge ids),
// srcv (src sorted by dst) and off[] — all coalesced writebacks.
// LDS ~82 KB, grid is only 391 blocks so occupancy is grid-limited anyway.
// ---------------------------------------------------------------------------
__global__ __launch_bounds__(256) void k_bsort(
    const int2* __restrict__ ebuf, const int* __restrict__ boff,
    int* __restrict__ csr, int* __restrict__ srcv,
    int* __restrict__ off, int E)
{
    __shared__ int2 stash[CAPB];
    __shared__ int sortE[CAPB];
    __shared__ int sortS[CAPB];
    __shared__ int hist[128];
    __shared__ int loff[129];
    __shared__ int cur[128];
    const int b   = blockIdx.x;
    const int beg = boff[b];
    const int cnt = boff[b + 1] - beg;
    for (int i = threadIdx.x; i < 128; i += 256) hist[i] = 0;
    __syncthreads();
    for (int i = threadIdx.x; i < cnt; i += 256) {
        int2 w = ebuf[beg + i];
        stash[i] = w;
        atomicAdd(&hist[w.x & BMASK], 1);
    }
    __syncthreads();
    if (threadIdx.x == 0) {
        int run = 0;
        loff[0] = 0;
        for (int i = 0; i < 128; ++i) { run += hist[i]; loff[i + 1] = run; }
    }
    __syncthreads();
    for (int i = threadIdx.x; i < 128; i += 256) cur[i] = loff[i];
    __syncthreads();
    for (int i = threadIdx.x; i < cnt; i += 256) {
        int2 w = stash[i];
        int p = atomicAdd(&cur[w.x & BMASK], 1);
        sortE[p] = w.x >> BSH;                // recover edge id
        sortS[p] = w.y;                       // src travels with it
    }
    __syncthreads();
    for (int i = threadIdx.x; i < cnt; i += 256) {
        csr[beg + i]  = sortE[i];
        srcv[beg + i] = sortS[i];
    }
    const int n0 = b << BSH;
    const int nn = min(128, N_NODES - n0);
    for (int j = threadIdx.x; j < nn; j += 256) off[n0 + j] = beg + loff[j];
    if (b == NBUCK - 1 && threadIdx.x == 0) off[N_NODES] = E;
}

// ---------------------------------------------------------------------------
// C1: mean[n] = sum of ef rows of n's in-edges / max(deg,1), stored fp16
// (3.2 MB table -> fits per-XCD L2 for the next kernel's gather).
// 32 lanes per node, unroll x8 for 8 outstanding 128B row reads.
// ---------------------------------------------------------------------------
__global__ __launch_bounds__(256) void k_node_mean(
    const float* __restrict__ ef, const int* __restrict__ csr,
    const int* __restrict__ off, __half* __restrict__ meanh)
{
    int n = blockIdx.x * 8 + (threadIdx.x >> 5);
    if (n >= N_NODES) return;
    int d = threadIdx.x & 31;
    int beg = off[n], end = off[n + 1];
    float a0 = 0.f, a1 = 0.f, a2 = 0.f, a3 = 0.f;
    float a4 = 0.f, a5 = 0.f, a6 = 0.f, a7 = 0.f;
    int i = beg;
    for (; i + 8 <= end; i += 8) {
        int e0 = csr[i],     e1 = csr[i + 1], e2 = csr[i + 2], e3 = csr[i + 3];
        int e4 = csr[i + 4], e5 = csr[i + 5], e6 = csr[i + 6], e7 = csr[i + 7];
        a0 += ef[(size_t)e0 * 32 + d];
        a1 += ef[(size_t)e1 * 32 + d];
        a2 += ef[(size_t)e2 * 32 + d];
        a3 += ef[(size_t)e3 * 32 + d];
        a4 += ef[(size_t)e4 * 32 + d];
        a5 += ef[(size_t)e5 * 32 + d];
        a6 += ef[(size_t)e6 * 32 + d];
        a7 += ef[(size_t)e7 * 32 + d];
    }
    for (; i < end; ++i) a0 += ef[(size_t)csr[i] * 32 + d];
    float s = ((a0 + a1) + (a2 + a3)) + ((a4 + a5) + (a6 + a7));
    meanh[(size_t)n * 32 + d] = __float2half(s / fmaxf((float)(end - beg), 1.0f));
}

// ---------------------------------------------------------------------------
// C2: fused h + g. srcv is now a sequential stream (no src[csr[i]] hop);
// mean gather is fp16 rows from an L2-resident 3.2 MB table. Unroll x8.
// Then 32x32 matmul g = h @ W^T, coalesced store of g.
// ---------------------------------------------------------------------------
__global__ __launch_bounds__(256) void k_node_hg(
    const __half* __restrict__ meanh, const int* __restrict__ srcv,
    const int* __restrict__ off, const float* __restrict__ W,
    float* __restrict__ g)
{
    __shared__ float sh[32][36];
    const int t   = threadIdx.x;
    const int d   = t & 31;
    const int grp = t >> 5;          // 0..7
    const int n0  = blockIdx.x * 32;
#pragma unroll
    for (int r = 0; r < 4; ++r) {
        int n = n0 + r * 8 + grp;
        float a0 = 0.f, a1 = 0.f, a2 = 0.f, a3 = 0.f;
        float a4 = 0.f, a5 = 0.f, a6 = 0.f, a7 = 0.f;
        if (n < N_NODES) {
            int beg = off[n], end = off[n + 1];
            int i = beg;
            for (; i + 8 <= end; i += 8) {
                int s0 = srcv[i],     s1 = srcv[i + 1];
                int s2 = srcv[i + 2], s3 = srcv[i + 3];
                int s4 = srcv[i + 4], s5 = srcv[i + 5];
                int s6 = srcv[i + 6], s7 = srcv[i + 7];
                a0 += __half2float(meanh[(size_t)s0 * 32 + d]);
                a1 += __half2float(meanh[(size_t)s1 * 32 + d]);
                a2 += __half2float(meanh[(size_t)s2 * 32 + d]);
                a3 += __half2float(meanh[(size_t)s3 * 32 + d]);
                a4 += __half2float(meanh[(size_t)s4 * 32 + d]);
                a5 += __half2float(meanh[(size_t)s5 * 32 + d]);
                a6 += __half2float(meanh[(size_t)s6 * 32 + d]);
                a7 += __half2float(meanh[(size_t)s7 * 32 + d]);
            }
            for (; i < end; ++i)
                a0 += __half2float(meanh[(size_t)srcv[i] * 32 + d]);
        }
        sh[r * 8 + grp][d] = ((a0 + a1) + (a2 + a3)) + ((a4 + a5) + (a6 + a7));
    }
    __syncthreads();
    // ---- g = h @ W^T for these 32 nodes
    const int j  = t & 31;
    const int rb = t >> 5;
    float w[32];
#pragma unroll
    for (int k = 0; k < 8; ++k) {
        float4 wv = *(const float4*)(W + j * 32 + k * 4);
        w[4 * k + 0] = wv.x;
        w[4 * k + 1] = wv.y;
        w[4 * k + 2] = wv.z;
        w[4 * k + 3] = wv.w;
    }
    float a0 = 0.f, a1 = 0.f, a2 = 0.f, a3 = 0.f;
#pragma unroll
    for (int dd = 0; dd < 32; ++dd) {
        float wd = w[dd];
        a0 += sh[rb +  0][dd] * wd;
        a1 += sh[rb +  8][dd] * wd;
        a2 += sh[rb + 16][dd] * wd;
        a3 += sh[rb + 24][dd] * wd;
    }
    if (n0 + rb +  0 < N_NODES) g[(size_t)(n0 + rb +  0) * 32 + j] = a0;
    if (n0 + rb +  8 < N_NODES) g[(size_t)(n0 + rb +  8) * 32 + j] = a1;
    if (n0 + rb + 16 < N_NODES) g[(size_t)(n0 + rb + 16) * 32 + j] = a2;
    if (n0 + rb + 24 < N_NODES) g[(size_t)(n0 + rb + 24) * 32 + j] = a3;
}

// ---------------------------------------------------------------------------
// C3: out[e] = 0.5*(g[src]+g[dst]) + b. 8 lanes x float4 per edge;
// fully coalesced 128B output runs.
// ---------------------------------------------------------------------------
__global__ __launch_bounds__(256) void k_edge_out2(
    const float* __restrict__ g, const int* __restrict__ src,
    const int* __restrict__ dst, const float* __restrict__ b,
    float* __restrict__ out, int E)
{
    int t = blockIdx.x * 256 + threadIdx.x;
    int e = t >> 3;
    if (e >= E) return;
    int d4 = (t & 7) << 2;
    int s = src[e];
    int n = dst[e];
    float4 a  = *(const float4*)(g + (size_t)s * 32 + d4);
    float4 c  = *(const float4*)(g + (size_t)n * 32 + d4);
    float4 bv = *(const float4*)(b + d4);
    float4 o;
    o.x = 0.5f * (a.x + c.x) + bv.x;
    o.y = 0.5f * (a.y + c.y) + bv.y;
    o.z = 0.5f * (a.z + c.z) + bv.z;
    o.w = 0.5f * (a.w + c.w) + bv.w;
    *(float4*)(out + (size_t)e * 32 + d4) = o;
}

extern "C" void kernel_launch(void* const* d_in, const int* in_sizes, int n_in,
                              void* d_out, int out_size, void* d_ws, size_t ws_size,
                              hipStream_t stream)
{
    const float* ef  = (const float*)d_in[0];
    const int*   src = (const int*)d_in[1];
    const int*   dst = (const int*)d_in[2];
    const float* W   = (const float*)d_in[3];
    const float* b   = (const float*)d_in[4];
    float*       out = (float*)d_out;
    const int E = in_sizes[1];

    // ---- workspace carve (16B-aligned chunks) ----
    int*    bcnt  = (int*)d_ws;           // 512
    int*    boff  = bcnt + 512;           // 512 (NBUCK+1 used)
    int*    bcur  = boff + 512;           // 512
    int*    off   = bcur + 512;           // 50016
    int2*   ebuf2 = (int2*)(off + 50016); // E int2 (byte off 206208, 8B-aligned)
    int*    csr   = (int*)(ebuf2 + E);    // E
    int*    srcv  = csr + E;              // E
    __half* meanh = (__half*)(srcv + E);  // N*32 halves (3.2 MB)
    float*  g     = (float*)((char*)meanh + (size_t)N_NODES * 32 * sizeof(__half));

    hipMemsetAsync(bcnt, 0, 512 * sizeof(int), stream);

    const int abk = (E + EPB - 1) / EPB;   // 391
    k_bhist<<<abk, 256, 0, stream>>>(dst, bcnt, E);
    k_bscan<<<1, 512, 0, stream>>>(bcnt, boff, bcur, E);
    k_bfill<<<abk, 256, 0, stream>>>(dst, src, bcur, ebuf2, E);
    k_bsort<<<NBUCK, 256, 0, stream>>>(ebuf2, boff, csr, srcv, off, E);

    k_node_mean<<<(N_NODES + 7) / 8, 256, 0, stream>>>(ef, csr, off, meanh);
    k_node_hg<<<(N_NODES + 31) / 32, 256, 0, stream>>>(meanh, srcv, off, W, g);

    const int oblk = (E * 8 + 255) / 256;
    k_edge_out2<<<oblk, 256, 0, stream>>>(g, src, dst, b, out, E);
}